// Round 8
// baseline (663.153 us; speedup 1.0000x reference)
//
#include <hip/hip_runtime.h>
#include <math.h>

#define NN 8192
#define KDIM 512
#define DD 256
#define CS 32      // prefix chunk size
#define NC 256     // number of chunks
#define NB 512     // cooperative grid blocks

typedef float4 f4;
typedef __attribute__((ext_vector_type(4))) float f4v;  // native vec for nontemporal

__device__ __forceinline__ float dot4(const f4& x, const f4& y) {
  return x.x * y.x + x.y * y.y + x.z * y.z + x.w * y.w;
}

// Single-counter grid barrier (validated at NB=256 in R6). Co-residency via
// cooperative launch. threadfence gives cross-XCD L2 visibility.
__device__ __forceinline__ void gridbar(unsigned* cnt, unsigned* gen) {
  __syncthreads();
  if (threadIdx.x == 0) {
    __threadfence();
    unsigned g = __hip_atomic_load(gen, __ATOMIC_RELAXED, __HIP_MEMORY_SCOPE_AGENT);
    unsigned a = __hip_atomic_fetch_add(cnt, 1u, __ATOMIC_ACQ_REL, __HIP_MEMORY_SCOPE_AGENT);
    if (a == NB - 1) {
      __hip_atomic_store(cnt, 0u, __ATOMIC_RELAXED, __HIP_MEMORY_SCOPE_AGENT);
      __hip_atomic_store(gen, g + 1u, __ATOMIC_RELEASE, __HIP_MEMORY_SCOPE_AGENT);
    } else {
      while (__hip_atomic_load(gen, __ATOMIC_ACQUIRE, __HIP_MEMORY_SCOPE_AGENT) == g)
        __builtin_amdgcn_s_sleep(1);
    }
    __threadfence();
  }
  __syncthreads();
}

// Cooperative kernel, 512 blocks: gemm(+s,t) | rank/E/c | chunk | prefix | finalize
__global__ __launch_bounds__(256, 2) void k_pre(const float* __restrict__ X,
                                                const float* __restrict__ W,
                                                const float* __restrict__ av,
                                                float* __restrict__ out,
                                                float* __restrict__ Ab,
                                                float* __restrict__ wsp) {
  // ws vector map
  float* s  = wsp + 0 * NN;
  float* t  = wsp + 1 * NN;
  float* E1 = wsp + 2 * NN;
  float* E2 = wsp + 3 * NN;
  float* c1 = wsp + 4 * NN;
  float* c2 = wsp + 5 * NN;
  float* f1 = wsp + 6 * NN;
  float* f2 = wsp + 7 * NN;
  // A-region scratch (dead before k_astream overwrites it)
  float* H     = out;
  float* PRE1  = Ab;                    // 8193*256 (slot padded to 4194304)
  float* PRE2  = Ab + 4194304;
  float* Ctot1 = Ab + 8388608;          // NC*DD
  float* Ctot2 = Ctot1 + NC * DD;
  float* cs1   = Ctot2 + NC * DD;       // NC
  float* cs2   = cs1 + NC;
  float* p1s   = cs2 + NC;              // NN+1
  float* p2s   = p1s + (NN + 256);
  float* tsort = p2s + (NN + 256);      // NN
  int*   perm  = (int*)(tsort + NN);    // NN
  unsigned* bcnt = (unsigned*)(Ab + 8600000);  // zeroed by memsetAsync
  unsigned* bgen = bcnt + 1;

  __shared__ float smem4[4096];         // gemm tiles: Xs[32][64] | Ws[32][64]
  __shared__ float sa[NC], sb[NC];
  __shared__ int   pms[CS];
  __shared__ float pe1[CS], pe2[CS];
  __shared__ float lred[4];

  const int b = blockIdx.x;
  const int tid = threadIdx.x;
  const int wid = tid >> 6, lane = tid & 63;

  // ================= phase A: GEMM 64x64 tile + s,t tail (R5-verbatim) =======
  {
    float (*Xs)[64] = (float(*)[64])smem4;          // [32][64] transposed [k][r]
    float (*Ws)[64] = (float(*)[64])(smem4 + 2048); // [32][64]
    const int tx = tid & 15;
    const int ty = tid >> 4;
    const int r0 = (b >> 2) * 64;
    const int c0 = (b & 3) * 64;
    float acc[4][4] = {};
    for (int k0 = 0; k0 < KDIM; k0 += 32) {
#pragma unroll
      for (int q = 0; q < 2; ++q) {
        int fi = tid + q * 256;
        int r = fi >> 3;
        int kq = fi & 7;
        f4 v = *reinterpret_cast<const f4*>(&X[(size_t)(r0 + r) * KDIM + k0 + kq * 4]);
        Xs[kq * 4 + 0][r] = v.x; Xs[kq * 4 + 1][r] = v.y;
        Xs[kq * 4 + 2][r] = v.z; Xs[kq * 4 + 3][r] = v.w;
      }
#pragma unroll
      for (int q = 0; q < 2; ++q) {
        int fi = tid + q * 256;
        int k = fi >> 4;
        int cq = fi & 15;
        *reinterpret_cast<f4*>(&Ws[k][cq * 4]) =
            *reinterpret_cast<const f4*>(&W[(size_t)(k0 + k) * DD + c0 + cq * 4]);
      }
      __syncthreads();
#pragma unroll
      for (int k = 0; k < 32; ++k) {
        f4 xv = *reinterpret_cast<const f4*>(&Xs[k][ty * 4]);
        f4 wv = *reinterpret_cast<const f4*>(&Ws[k][tx * 4]);
        float xs[4] = {xv.x, xv.y, xv.z, xv.w};
        float ws[4] = {wv.x, wv.y, wv.z, wv.w};
#pragma unroll
        for (int i = 0; i < 4; ++i)
#pragma unroll
          for (int j = 0; j < 4; ++j) acc[i][j] += xs[i] * ws[j];
      }
      __syncthreads();
    }
#pragma unroll
    for (int i = 0; i < 4; ++i) {
      f4 v = {acc[i][0], acc[i][1], acc[i][2], acc[i][3]};
      *reinterpret_cast<f4*>(&H[(size_t)(r0 + ty * 4 + i) * DD + c0 + tx * 4]) = v;
    }

    if ((b & 3) == 0) {
      // s,t for rows r0..r0+63 via s = X@(W@a1), t = X@(W@a2)
      float* wv1 = smem4;        // [512]
      float* wv2 = smem4 + 512;  // [512]
      for (int k = tid; k < KDIM; k += 256) {
        float a1acc = 0.f, a2acc = 0.f;
#pragma unroll 8
        for (int d4 = 0; d4 < DD / 4; ++d4) {
          f4 wrow = *reinterpret_cast<const f4*>(&W[(size_t)k * DD + d4 * 4]);
          f4 a1v = *reinterpret_cast<const f4*>(&av[d4 * 4]);
          f4 a2v = *reinterpret_cast<const f4*>(&av[DD + d4 * 4]);
          a1acc += dot4(wrow, a1v);
          a2acc += dot4(wrow, a2v);
        }
        wv1[k] = a1acc;
        wv2[k] = a2acc;
      }
      __syncthreads();
      f4 w1a = *reinterpret_cast<const f4*>(&wv1[lane * 8]);
      f4 w1b = *reinterpret_cast<const f4*>(&wv1[lane * 8 + 4]);
      f4 w2a = *reinterpret_cast<const f4*>(&wv2[lane * 8]);
      f4 w2b = *reinterpret_cast<const f4*>(&wv2[lane * 8 + 4]);
      for (int rr = 0; rr < 16; ++rr) {
        int i = r0 + wid * 16 + rr;
        f4 xa = *reinterpret_cast<const f4*>(&X[(size_t)i * KDIM + lane * 8]);
        f4 xb = *reinterpret_cast<const f4*>(&X[(size_t)i * KDIM + lane * 8 + 4]);
        float p1 = dot4(xa, w1a) + dot4(xb, w1b);
        float p2 = dot4(xa, w2a) + dot4(xb, w2b);
        for (int off = 32; off > 0; off >>= 1) {
          p1 += __shfl_down(p1, off);
          p2 += __shfl_down(p2, off);
        }
        if (lane == 0) { s[i] = p1; t[i] = p2; }
      }
    }
  }
  gridbar(bcnt, bgen);  // H, s, t complete

  // ============ phase B: tmax (global stream), E/c (16 rows), rank 16 keys ====
  {
    float m = -1e30f;
#pragma unroll
    for (int q = 0; q < 8; ++q) {
      int idx = (q * 256 + tid) * 4;
      f4 v = *reinterpret_cast<const f4*>(&t[idx]);
      m = fmaxf(m, fmaxf(fmaxf(v.x, v.y), fmaxf(v.z, v.w)));
    }
    for (int off = 32; off > 0; off >>= 1) m = fmaxf(m, __shfl_down(m, off));
    if (lane == 0) lred[wid] = m;
    __syncthreads();
    float tmax = fmaxf(fmaxf(lred[0], lred[1]), fmaxf(lred[2], lred[3]));

    if (tid < 16) {
      int i = b * 16 + tid;
      float ti = t[i];
      E1[i] = expf(ti);
      E2[i] = expf(0.2f * ti);
      float si = s[i];
      float e = si + tmax;
      float mm = e > 0.f ? e : 0.2f * e;
      c1[i] = expf(si - mm);
      c2[i] = expf(0.2f * si - mm);
    }

    // rank 16 keys/block, 4 per wave (wave-uniform keys, per-lane value slices)
    float tkv[4]; int jj[4]; int cnt[4];
#pragma unroll
    for (int q = 0; q < 4; ++q) {
      jj[q] = b * 16 + wid * 4 + q;
      tkv[q] = t[jj[q]];
      cnt[q] = 0;
    }
    for (int m2 = 0; m2 < 32; ++m2) {
      int i4 = m2 * 64 + lane;
      f4 v = *reinterpret_cast<const f4*>(&t[i4 * 4]);
      int base = i4 * 4;
#pragma unroll
      for (int q = 0; q < 4; ++q) {
        cnt[q] += (v.x < tkv[q]) || (v.x == tkv[q] && base + 0 < jj[q]);
        cnt[q] += (v.y < tkv[q]) || (v.y == tkv[q] && base + 1 < jj[q]);
        cnt[q] += (v.z < tkv[q]) || (v.z == tkv[q] && base + 2 < jj[q]);
        cnt[q] += (v.w < tkv[q]) || (v.w == tkv[q] && base + 3 < jj[q]);
      }
    }
#pragma unroll
    for (int q = 0; q < 4; ++q) {
      int c = cnt[q];
      for (int off = 32; off > 0; off >>= 1) c += __shfl_down(c, off);
      if (lane == 0) { tsort[c] = tkv[q]; perm[c] = jj[q]; }
    }
  }
  gridbar(bcnt, bgen);  // E1, E2, c1, c2, tsort, perm complete

  // ================= phase C: chunk totals (blocks 0..255) =================
  if (b < NC) {
    int d = tid;
    if (d < CS) {
      int p = perm[b * CS + d];
      pms[d] = p;
      pe1[d] = E1[p];
      pe2[d] = E2[p];
    }
    __syncthreads();
    float s1 = 0.f, s2 = 0.f, a1 = 0.f, a2 = 0.f;
#pragma unroll 4
    for (int kk = 0; kk < CS; ++kk) {
      float e1 = pe1[kk], e2 = pe2[kk];
      float h = H[(size_t)pms[kk] * DD + d];
      s1 += e1 * h; s2 += e2 * h;
      a1 += e1;     a2 += e2;
    }
    Ctot1[b * DD + d] = s1;
    Ctot2[b * DD + d] = s2;
    if (d == 0) { cs1[b] = a1; cs2[b] = a2; }
  }
  gridbar(bcnt, bgen);  // Ctot, cs complete

  // ================= phase D: exclusive prefix (blocks 0..255) =================
  if (b < NC) {
    int d = tid;
    float r1a = 0.f, r1b = 0.f, r2a = 0.f, r2b = 0.f;
    int cc = 0;
    for (; cc + 4 <= b; cc += 4) {
      r1a += Ctot1[(cc + 0) * DD + d];
      r1b += Ctot1[(cc + 1) * DD + d];
      r1a += Ctot1[(cc + 2) * DD + d];
      r1b += Ctot1[(cc + 3) * DD + d];
      r2a += Ctot2[(cc + 0) * DD + d];
      r2b += Ctot2[(cc + 1) * DD + d];
      r2a += Ctot2[(cc + 2) * DD + d];
      r2b += Ctot2[(cc + 3) * DD + d];
    }
    for (; cc < b; ++cc) {
      r1a += Ctot1[cc * DD + d];
      r2a += Ctot2[cc * DD + d];
    }
    float r1 = r1a + r1b, r2 = r2a + r2b;
    if (d < CS) {
      int p = perm[b * CS + d];
      pms[d] = p;
      pe1[d] = E1[p];
      pe2[d] = E2[p];
    }
    sa[d] = (d < b) ? cs1[d] : 0.f;
    sb[d] = (d < b) ? cs2[d] : 0.f;
    __syncthreads();
    for (int off = 128; off > 0; off >>= 1) {
      if (d < off) { sa[d] += sa[d + off]; sb[d] += sb[d + off]; }
      __syncthreads();
    }
    float sr1 = sa[0], sr2 = sb[0];
#pragma unroll 2
    for (int kk = 0; kk < CS; ++kk) {
      int k = b * CS + kk;
      PRE1[(size_t)k * DD + d] = r1;
      PRE2[(size_t)k * DD + d] = r2;
      float e1 = pe1[kk], e2 = pe2[kk];
      float h = H[(size_t)pms[kk] * DD + d];
      r1 += e1 * h; r2 += e2 * h;
      if (d == 0) { p1s[k] = sr1; p2s[k] = sr2; sr1 += e1; sr2 += e2; }
    }
    if (b == NC - 1) {
      PRE1[(size_t)NN * DD + d] = r1;
      PRE2[(size_t)NN * DD + d] = r2;
      if (d == 0) { p1s[NN] = sr1; p2s[NN] = sr2; }
    }
  }
  gridbar(bcnt, bgen);  // PRE, p1s, p2s complete

  // ====== phase E: finalize rows b*16..b*16+15 (4/wave, interleaved search) ====
  {
    float key[4];
    int lo[4] = {0, 0, 0, 0}, hi[4] = {NN, NN, NN, NN};
#pragma unroll
    for (int q = 0; q < 4; ++q) key[q] = -s[b * 16 + wid * 4 + q];
    for (int step = 0; step < 14; ++step) {
      int mid[4]; float v[4];
#pragma unroll
      for (int q = 0; q < 4; ++q) { mid[q] = (lo[q] + hi[q]) >> 1; v[q] = tsort[mid[q]]; }
#pragma unroll
      for (int q = 0; q < 4; ++q) {
        if (lo[q] < hi[q]) {
          if (v[q] <= key[q]) lo[q] = mid[q] + 1; else hi[q] = mid[q];
        }
      }
    }
    int d = lane * 4;
    f4 T1 = *reinterpret_cast<const f4*>(&PRE1[(size_t)NN * DD + d]);
    float tot1 = p1s[NN];
#pragma unroll
    for (int q = 0; q < 4; ++q) {
      int i = b * 16 + wid * 4 + q;
      int k = lo[q];
      float cc1 = c1[i], cc2 = c2[i];
      float Z = cc1 * (tot1 - p1s[k]) + cc2 * p2s[k];
      float rZ = 1.0f / Z;
      if (lane == 0) { f1[i] = rZ * cc1; f2[i] = rZ * cc2; }
      f4 P1 = *reinterpret_cast<const f4*>(&PRE1[(size_t)k * DD + d]);
      f4 P2 = *reinterpret_cast<const f4*>(&PRE2[(size_t)k * DD + d]);
      f4 o;
      o.x = rZ * (cc1 * (T1.x - P1.x) + cc2 * P2.x);
      o.y = rZ * (cc1 * (T1.y - P1.y) + cc2 * P2.y);
      o.z = rZ * (cc1 * (T1.z - P1.z) + cc2 * P2.z);
      o.w = rZ * (cc1 * (T1.w - P1.w) + cc2 * P2.w);
      *reinterpret_cast<f4*>(&out[(size_t)i * DD + d]) = o;
    }
  }
}

// ---------- K3: stream A = (s_i + t_j > 0) ? f1_i*E1_j : f2_i*E2_j ----------
__global__ __launch_bounds__(256) void k_astream(const float* __restrict__ s,
                                                 const float* __restrict__ t,
                                                 const float* __restrict__ E1,
                                                 const float* __restrict__ E2,
                                                 const float* __restrict__ f1,
                                                 const float* __restrict__ f2,
                                                 float* __restrict__ A) {
  int j0 = blockIdx.x * 1024 + threadIdx.x * 4;
  int i0 = blockIdx.y * 32;
  f4 t4  = *reinterpret_cast<const f4*>(&t[j0]);
  f4 e14 = *reinterpret_cast<const f4*>(&E1[j0]);
  f4 e24 = *reinterpret_cast<const f4*>(&E2[j0]);
#pragma unroll 4
  for (int rr = 0; rr < 32; ++rr) {
    int i = i0 + rr;
    float ss = s[i], ff1 = f1[i], ff2 = f2[i];
    f4v o;
    float e;
    e = ss + t4.x; o.x = (e > 0.f) ? ff1 * e14.x : ff2 * e24.x;
    e = ss + t4.y; o.y = (e > 0.f) ? ff1 * e14.y : ff2 * e24.y;
    e = ss + t4.z; o.z = (e > 0.f) ? ff1 * e14.z : ff2 * e24.z;
    e = ss + t4.w; o.w = (e > 0.f) ? ff1 * e14.w : ff2 * e24.w;
    __builtin_nontemporal_store(o, reinterpret_cast<f4v*>(&A[(size_t)i * NN + j0]));
  }
}

extern "C" void kernel_launch(void* const* d_in, const int* in_sizes, int n_in,
                              void* d_out, int out_size, void* d_ws, size_t ws_size,
                              hipStream_t stream) {
  const float* X  = (const float*)d_in[0];
  const float* W  = (const float*)d_in[1];
  const float* av = (const float*)d_in[2];
  float* outp = (float*)d_out;                  // [NN*DD]
  float* Ap   = outp + (size_t)NN * DD;         // [NN*NN]
  float* wsp  = (float*)d_ws;

  float* s  = wsp + 0 * NN;
  float* t  = wsp + 1 * NN;
  float* E1 = wsp + 2 * NN;
  float* E2 = wsp + 3 * NN;
  float* f1 = wsp + 6 * NN;
  float* f2 = wsp + 7 * NN;

  // zero the grid-barrier words (cnt, gen)
  hipMemsetAsync((void*)(Ap + 8600000), 0, 8, stream);

  void* cargs[] = {(void*)&X, (void*)&W, (void*)&av,
                   (void*)&outp, (void*)&Ap, (void*)&wsp};
  hipLaunchCooperativeKernel((void*)k_pre, dim3(NB), dim3(256), cargs, 0, stream);

  k_astream<<<dim3(NN / 1024, NN / 32), 256, 0, stream>>>(s, t, E1, E2, f1, f2, Ap);
}

// Round 9
// 316.143 us; speedup vs baseline: 2.0976x; 2.0976x over previous
//
#include <hip/hip_runtime.h>
#include <math.h>

#define NN 8192
#define KDIM 512
#define DD 256
#define CS 32      // prefix chunk size
#define NC 256     // number of chunks

typedef float4 f4;
typedef __attribute__((ext_vector_type(4))) float f4v;  // native vec for nontemporal

__device__ __forceinline__ float dot4(const f4& x, const f4& y) {
  return x.x * y.x + x.y * y.y + x.z * y.z + x.w * y.w;
}

// ---------- K1: H = X @ W (f32 vector GEMM, 64x64 tile) + s,t tail ----------
__global__ __launch_bounds__(256) void k_gemm(const float* __restrict__ X,
                                              const float* __restrict__ W,
                                              const float* __restrict__ av,
                                              float* __restrict__ H,
                                              float* __restrict__ s,
                                              float* __restrict__ t) {
  __shared__ float Xs[32][64];  // [k][r] (transposed); reused as wv1/wv2 after
  __shared__ float Ws[32][64];  // [k][c]
  const int tid = threadIdx.x;
  const int tx = tid & 15;
  const int ty = tid >> 4;
  const int r0 = blockIdx.x * 64;
  const int c0 = blockIdx.y * 64;
  float acc[4][4] = {};
  for (int k0 = 0; k0 < KDIM; k0 += 32) {
#pragma unroll
    for (int q = 0; q < 2; ++q) {
      int fi = tid + q * 256;
      int r = fi >> 3;
      int kq = fi & 7;
      f4 v = *reinterpret_cast<const f4*>(&X[(size_t)(r0 + r) * KDIM + k0 + kq * 4]);
      Xs[kq * 4 + 0][r] = v.x; Xs[kq * 4 + 1][r] = v.y;
      Xs[kq * 4 + 2][r] = v.z; Xs[kq * 4 + 3][r] = v.w;
    }
#pragma unroll
    for (int q = 0; q < 2; ++q) {
      int fi = tid + q * 256;
      int k = fi >> 4;
      int cq = fi & 15;
      *reinterpret_cast<f4*>(&Ws[k][cq * 4]) =
          *reinterpret_cast<const f4*>(&W[(size_t)(k0 + k) * DD + c0 + cq * 4]);
    }
    __syncthreads();
#pragma unroll
    for (int k = 0; k < 32; ++k) {
      f4 xv = *reinterpret_cast<const f4*>(&Xs[k][ty * 4]);
      f4 wv = *reinterpret_cast<const f4*>(&Ws[k][tx * 4]);
      float xs[4] = {xv.x, xv.y, xv.z, xv.w};
      float ws[4] = {wv.x, wv.y, wv.z, wv.w};
#pragma unroll
      for (int i = 0; i < 4; ++i)
#pragma unroll
        for (int j = 0; j < 4; ++j) acc[i][j] += xs[i] * ws[j];
    }
    __syncthreads();
  }
#pragma unroll
  for (int i = 0; i < 4; ++i) {
    f4 v = {acc[i][0], acc[i][1], acc[i][2], acc[i][3]};
    *reinterpret_cast<f4*>(&H[(size_t)(r0 + ty * 4 + i) * DD + c0 + tx * 4]) = v;
  }

  if (c0 == 0) {
    // s,t for rows r0..r0+63 via s = X@(W@a1), t = X@(W@a2)
    int wid = tid >> 6, lane = tid & 63;
    float* wv1 = &Xs[0][0];        // [512]
    float* wv2 = &Xs[0][0] + 512;  // [512]
    for (int k = tid; k < KDIM; k += 256) {
      float a1acc = 0.f, a2acc = 0.f;
#pragma unroll 8
      for (int d4 = 0; d4 < DD / 4; ++d4) {
        f4 wrow = *reinterpret_cast<const f4*>(&W[(size_t)k * DD + d4 * 4]);
        f4 a1v = *reinterpret_cast<const f4*>(&av[d4 * 4]);
        f4 a2v = *reinterpret_cast<const f4*>(&av[DD + d4 * 4]);
        a1acc += dot4(wrow, a1v);
        a2acc += dot4(wrow, a2v);
      }
      wv1[k] = a1acc;
      wv2[k] = a2acc;
    }
    __syncthreads();
    f4 w1a = *reinterpret_cast<const f4*>(&wv1[lane * 8]);
    f4 w1b = *reinterpret_cast<const f4*>(&wv1[lane * 8 + 4]);
    f4 w2a = *reinterpret_cast<const f4*>(&wv2[lane * 8]);
    f4 w2b = *reinterpret_cast<const f4*>(&wv2[lane * 8 + 4]);
    for (int rr = 0; rr < 16; ++rr) {
      int i = r0 + wid * 16 + rr;
      f4 xa = *reinterpret_cast<const f4*>(&X[(size_t)i * KDIM + lane * 8]);
      f4 xb = *reinterpret_cast<const f4*>(&X[(size_t)i * KDIM + lane * 8 + 4]);
      float p1 = dot4(xa, w1a) + dot4(xb, w1b);
      float p2 = dot4(xa, w2a) + dot4(xb, w2b);
      for (int off = 32; off > 0; off >>= 1) {
        p1 += __shfl_down(p1, off);
        p2 += __shfl_down(p2, off);
      }
      if (lane == 0) { s[i] = p1; t[i] = p2; }
    }
  }
}

// ---------- K2: tmax, E1/E2, c1/c2 (16 rows), rank 16 keys (512 blocks) -------
__global__ __launch_bounds__(256) void k_mid(const float* __restrict__ s,
                                             const float* __restrict__ t,
                                             float* __restrict__ E1,
                                             float* __restrict__ E2,
                                             float* __restrict__ c1,
                                             float* __restrict__ c2,
                                             float* __restrict__ tsort,
                                             int* __restrict__ perm) {
  __shared__ float lred[4];
  const int b = blockIdx.x, tid = threadIdx.x;
  const int wid = tid >> 6, lane = tid & 63;
  float m = -1e30f;
#pragma unroll
  for (int q = 0; q < 8; ++q) {
    int idx = (q * 256 + tid) * 4;
    f4 v = *reinterpret_cast<const f4*>(&t[idx]);
    m = fmaxf(m, fmaxf(fmaxf(v.x, v.y), fmaxf(v.z, v.w)));
  }
  for (int off = 32; off > 0; off >>= 1) m = fmaxf(m, __shfl_down(m, off));
  if (lane == 0) lred[wid] = m;
  __syncthreads();
  float tmax = fmaxf(fmaxf(lred[0], lred[1]), fmaxf(lred[2], lred[3]));

  if (tid < 16) {
    int i = b * 16 + tid;
    float ti = t[i];
    E1[i] = expf(ti);
    E2[i] = expf(0.2f * ti);
    float si = s[i];
    float e = si + tmax;
    float mm = e > 0.f ? e : 0.2f * e;
    c1[i] = expf(si - mm);
    c2[i] = expf(0.2f * si - mm);
  }

  // rank 16 keys/block, 4 per wave (wave-uniform keys, per-lane value slices)
  float tkv[4]; int jj[4]; int cnt[4];
#pragma unroll
  for (int q = 0; q < 4; ++q) {
    jj[q] = b * 16 + wid * 4 + q;
    tkv[q] = t[jj[q]];
    cnt[q] = 0;
  }
  for (int m2 = 0; m2 < 32; ++m2) {
    int i4 = m2 * 64 + lane;
    f4 v = *reinterpret_cast<const f4*>(&t[i4 * 4]);
    int base = i4 * 4;
#pragma unroll
    for (int q = 0; q < 4; ++q) {
      cnt[q] += (v.x < tkv[q]) || (v.x == tkv[q] && base + 0 < jj[q]);
      cnt[q] += (v.y < tkv[q]) || (v.y == tkv[q] && base + 1 < jj[q]);
      cnt[q] += (v.z < tkv[q]) || (v.z == tkv[q] && base + 2 < jj[q]);
      cnt[q] += (v.w < tkv[q]) || (v.w == tkv[q] && base + 3 < jj[q]);
    }
  }
#pragma unroll
  for (int q = 0; q < 4; ++q) {
    int c = cnt[q];
    for (int off = 32; off > 0; off >>= 1) c += __shfl_down(c, off);
    if (lane == 0) { tsort[c] = tkv[q]; perm[c] = jj[q]; }
  }
}

// ---------- K3: per-chunk totals of E1*H / E2*H over sorted order ----------
__global__ __launch_bounds__(256) void k_chunk(const float* __restrict__ H,
                                               const float* __restrict__ E1,
                                               const float* __restrict__ E2,
                                               const int* __restrict__ perm,
                                               float* __restrict__ Ctot1,
                                               float* __restrict__ Ctot2,
                                               float* __restrict__ cs1,
                                               float* __restrict__ cs2) {
  __shared__ int pms[CS];
  __shared__ float pe1[CS], pe2[CS];
  int c = blockIdx.x;
  int d = threadIdx.x;
  if (d < CS) {
    int p = perm[c * CS + d];
    pms[d] = p;
    pe1[d] = E1[p];
    pe2[d] = E2[p];
  }
  __syncthreads();
  float s1 = 0.f, s2 = 0.f, a1 = 0.f, a2 = 0.f;
#pragma unroll 4
  for (int kk = 0; kk < CS; ++kk) {
    float e1 = pe1[kk], e2 = pe2[kk];
    float h = H[(size_t)pms[kk] * DD + d];
    s1 += e1 * h; s2 += e2 * h;
    a1 += e1;     a2 += e2;
  }
  Ctot1[c * DD + d] = s1;
  Ctot2[c * DD + d] = s2;
  if (d == 0) { cs1[c] = a1; cs2[c] = a2; }
}

// ---------- K4: fused prefix+finalize (no PRE arrays) ----------
// Block b owns rows b*32..b*32+31. Per row: binary-search k_i, chunk c_i,
// scalar Z from cs prefix + in-chunk E partial. Then ONE running-prefix sweep
// over Ctot emits each row (sorted by c_i) at its boundary:
//   out = g2*P2 - g1*P1, epilogue adds g1*T1 (same thread -> no race).
__global__ __launch_bounds__(256) void k_fin(const float* __restrict__ s,
                                             const float* __restrict__ c1,
                                             const float* __restrict__ c2,
                                             const float* __restrict__ tsort,
                                             const int* __restrict__ perm,
                                             const float* __restrict__ E1,
                                             const float* __restrict__ E2,
                                             const float* __restrict__ H,
                                             const float* __restrict__ Ctot1,
                                             const float* __restrict__ Ctot2,
                                             const float* __restrict__ cs1,
                                             const float* __restrict__ cs2,
                                             float* __restrict__ out,
                                             float* __restrict__ f1,
                                             float* __restrict__ f2) {
  __shared__ int   kiL[32], ciL[32], sIdx[32];
  __shared__ float g1L[32], g2L[32];
  __shared__ int   bndL[33];
  const int b = blockIdx.x;
  const int tid = threadIdx.x;

  // ---- stage: one thread per row ----
  if (tid < 32) {
    int i = b * 32 + tid;
    float key = -s[i];
    int lo = 0, hi = NN;
    while (lo < hi) {
      int mid = (lo + hi) >> 1;
      if (tsort[mid] <= key) lo = mid + 1; else hi = mid;
    }
    int ki = lo, ci = ki >> 5;   // ci in [0, NC]
    float tt1 = 0.f, sp1 = 0.f, sp2 = 0.f;
    for (int cc = 0; cc < NC; ++cc) {
      float v1 = cs1[cc];
      tt1 += v1;
      if (cc < ci) { sp1 += v1; sp2 += cs2[cc]; }
    }
    for (int m = ci * CS; m < ki; ++m) {
      int p = perm[m];
      sp1 += E1[p];
      sp2 += E2[p];
    }
    float a1 = c1[i], a2 = c2[i];
    float Z = a1 * (tt1 - sp1) + a2 * sp2;
    float rZ = 1.0f / Z;
    f1[i] = rZ * a1;
    f2[i] = rZ * a2;
    g1L[tid] = rZ * a1;
    g2L[tid] = rZ * a2;
    kiL[tid] = ki;
    ciL[tid] = ci;
  }
  __syncthreads();
  if (tid < 32) {
    // rank-sort rows by ci (ties by row index)
    int ci = ciL[tid];
    int rank = 0;
    for (int r2 = 0; r2 < 32; ++r2) {
      int cv = ciL[r2];
      rank += (cv < ci) || (cv == ci && r2 < tid);
    }
    sIdx[rank] = tid;
  }
  __syncthreads();
  if (tid < 33) bndL[tid] = (tid < 32) ? ciL[sIdx[tid]] : (NC + 1);
  __syncthreads();

  // ---- main: running prefix over Ctot + sorted emits ----
  const int d = tid;
  float run1 = 0.f, run2 = 0.f;
  int ptr = 0;
  int nextci = bndL[0];
  for (int cc = 0; cc <= NC; ++cc) {
    while (nextci == cc) {
      int r = sIdx[ptr];
      int ki = kiL[r];
      float P1 = run1, P2 = run2;
      for (int m = cc * CS; m < ki; ++m) {
        int p = perm[m];
        float h = H[(size_t)p * DD + d];
        P1 += E1[p] * h;
        P2 += E2[p] * h;
      }
      int i = b * 32 + r;
      out[(size_t)i * DD + d] = g2L[r] * P2 - g1L[r] * P1;
      ++ptr;
      nextci = bndL[ptr];
    }
    if (cc < NC) {
      run1 += Ctot1[cc * DD + d];
      run2 += Ctot2[cc * DD + d];
    }
  }
  float T1 = run1;
#pragma unroll 4
  for (int r = 0; r < 32; ++r) {
    int i = b * 32 + r;
    out[(size_t)i * DD + d] += g1L[r] * T1;
  }
}

// ---------- K5: stream A = (s_i + t_j > 0) ? f1_i*E1_j : f2_i*E2_j ----------
__global__ __launch_bounds__(256) void k_astream(const float* __restrict__ s,
                                                 const float* __restrict__ t,
                                                 const float* __restrict__ E1,
                                                 const float* __restrict__ E2,
                                                 const float* __restrict__ f1,
                                                 const float* __restrict__ f2,
                                                 float* __restrict__ A) {
  int j0 = blockIdx.x * 1024 + threadIdx.x * 4;
  int i0 = blockIdx.y * 32;
  f4 t4  = *reinterpret_cast<const f4*>(&t[j0]);
  f4 e14 = *reinterpret_cast<const f4*>(&E1[j0]);
  f4 e24 = *reinterpret_cast<const f4*>(&E2[j0]);
#pragma unroll 4
  for (int rr = 0; rr < 32; ++rr) {
    int i = i0 + rr;
    float ss = s[i], ff1 = f1[i], ff2 = f2[i];
    f4v o;
    float e;
    e = ss + t4.x; o.x = (e > 0.f) ? ff1 * e14.x : ff2 * e24.x;
    e = ss + t4.y; o.y = (e > 0.f) ? ff1 * e14.y : ff2 * e24.y;
    e = ss + t4.z; o.z = (e > 0.f) ? ff1 * e14.z : ff2 * e24.z;
    e = ss + t4.w; o.w = (e > 0.f) ? ff1 * e14.w : ff2 * e24.w;
    __builtin_nontemporal_store(o, reinterpret_cast<f4v*>(&A[(size_t)i * NN + j0]));
  }
}

extern "C" void kernel_launch(void* const* d_in, const int* in_sizes, int n_in,
                              void* d_out, int out_size, void* d_ws, size_t ws_size,
                              hipStream_t stream) {
  const float* X  = (const float*)d_in[0];
  const float* W  = (const float*)d_in[1];
  const float* av = (const float*)d_in[2];
  float* outp = (float*)d_out;                  // [NN*DD]
  float* A = outp + (size_t)NN * DD;            // [NN*NN]

  // small vectors in ws (256 KB)
  float* wsp = (float*)d_ws;
  float* s  = wsp + 0 * NN;
  float* t  = wsp + 1 * NN;
  float* E1 = wsp + 2 * NN;
  float* E2 = wsp + 3 * NN;
  float* c1 = wsp + 4 * NN;
  float* c2 = wsp + 5 * NN;
  float* f1 = wsp + 6 * NN;
  float* f2 = wsp + 7 * NN;

  // scratch in the A-region (consumed by k_fin before k_astream overwrites).
  // H lives at +64 MB so k_fin's out-writes never alias H reads.
  float* Ctot1 = A;                   // NC*DD
  float* Ctot2 = Ctot1 + NC * DD;
  float* cs1   = Ctot2 + NC * DD;     // NC
  float* cs2   = cs1 + NC;
  float* tsort = cs2 + NC;            // NN
  int*   perm  = (int*)(tsort + NN);  // NN
  float* H     = A + 16777216;        // [NN*DD] at +64 MB

  k_gemm<<<dim3(NN / 64, DD / 64), 256, 0, stream>>>(X, W, av, H, s, t);
  k_mid<<<NN / 16, 256, 0, stream>>>(s, t, E1, E2, c1, c2, tsort, perm);
  k_chunk<<<NC, 256, 0, stream>>>(H, E1, E2, perm, Ctot1, Ctot2, cs1, cs2);
  k_fin<<<NN / 32, 256, 0, stream>>>(s, c1, c2, tsort, perm, E1, E2, H,
                                     Ctot1, Ctot2, cs1, cs2, outp, f1, f2);
  k_astream<<<dim3(NN / 1024, NN / 32), 256, 0, stream>>>(s, t, E1, E2, f1, f2, A);
}

// Round 10
// 197.602 us; speedup vs baseline: 3.3560x; 1.5999x over previous
//
#include <hip/hip_runtime.h>
#include <math.h>

#define NN 8192
#define KDIM 512
#define DD 256
#define CS 32      // prefix chunk size
#define NC 256     // number of chunks

typedef float4 f4;
typedef __attribute__((ext_vector_type(4))) float f4v;  // native vec for nontemporal

__device__ __forceinline__ float dot4(const f4& x, const f4& y) {
  return x.x * y.x + x.y * y.y + x.z * y.z + x.w * y.w;
}

// ---------- K1: H = X @ W (f32 vector GEMM, 64x64 tile) + s,t tail ----------
__global__ __launch_bounds__(256) void k_gemm(const float* __restrict__ X,
                                              const float* __restrict__ W,
                                              const float* __restrict__ av,
                                              float* __restrict__ H,
                                              float* __restrict__ s,
                                              float* __restrict__ t) {
  __shared__ float Xs[32][64];  // [k][r] (transposed); reused as wv1/wv2 after
  __shared__ float Ws[32][64];  // [k][c]
  const int tid = threadIdx.x;
  const int tx = tid & 15;
  const int ty = tid >> 4;
  const int r0 = blockIdx.x * 64;
  const int c0 = blockIdx.y * 64;
  float acc[4][4] = {};
  for (int k0 = 0; k0 < KDIM; k0 += 32) {
#pragma unroll
    for (int q = 0; q < 2; ++q) {
      int fi = tid + q * 256;
      int r = fi >> 3;
      int kq = fi & 7;
      f4 v = *reinterpret_cast<const f4*>(&X[(size_t)(r0 + r) * KDIM + k0 + kq * 4]);
      Xs[kq * 4 + 0][r] = v.x; Xs[kq * 4 + 1][r] = v.y;
      Xs[kq * 4 + 2][r] = v.z; Xs[kq * 4 + 3][r] = v.w;
    }
#pragma unroll
    for (int q = 0; q < 2; ++q) {
      int fi = tid + q * 256;
      int k = fi >> 4;
      int cq = fi & 15;
      *reinterpret_cast<f4*>(&Ws[k][cq * 4]) =
          *reinterpret_cast<const f4*>(&W[(size_t)(k0 + k) * DD + c0 + cq * 4]);
    }
    __syncthreads();
#pragma unroll
    for (int k = 0; k < 32; ++k) {
      f4 xv = *reinterpret_cast<const f4*>(&Xs[k][ty * 4]);
      f4 wv = *reinterpret_cast<const f4*>(&Ws[k][tx * 4]);
      float xs[4] = {xv.x, xv.y, xv.z, xv.w};
      float ws[4] = {wv.x, wv.y, wv.z, wv.w};
#pragma unroll
      for (int i = 0; i < 4; ++i)
#pragma unroll
        for (int j = 0; j < 4; ++j) acc[i][j] += xs[i] * ws[j];
    }
    __syncthreads();
  }
#pragma unroll
  for (int i = 0; i < 4; ++i) {
    f4 v = {acc[i][0], acc[i][1], acc[i][2], acc[i][3]};
    *reinterpret_cast<f4*>(&H[(size_t)(r0 + ty * 4 + i) * DD + c0 + tx * 4]) = v;
  }

  if (c0 == 0) {
    // s,t for rows r0..r0+63 via s = X@(W@a1), t = X@(W@a2)
    int wid = tid >> 6, lane = tid & 63;
    float* wv1 = &Xs[0][0];        // [512]
    float* wv2 = &Xs[0][0] + 512;  // [512]
    for (int k = tid; k < KDIM; k += 256) {
      float a1acc = 0.f, a2acc = 0.f;
#pragma unroll 8
      for (int d4 = 0; d4 < DD / 4; ++d4) {
        f4 wrow = *reinterpret_cast<const f4*>(&W[(size_t)k * DD + d4 * 4]);
        f4 a1v = *reinterpret_cast<const f4*>(&av[d4 * 4]);
        f4 a2v = *reinterpret_cast<const f4*>(&av[DD + d4 * 4]);
        a1acc += dot4(wrow, a1v);
        a2acc += dot4(wrow, a2v);
      }
      wv1[k] = a1acc;
      wv2[k] = a2acc;
    }
    __syncthreads();
    f4 w1a = *reinterpret_cast<const f4*>(&wv1[lane * 8]);
    f4 w1b = *reinterpret_cast<const f4*>(&wv1[lane * 8 + 4]);
    f4 w2a = *reinterpret_cast<const f4*>(&wv2[lane * 8]);
    f4 w2b = *reinterpret_cast<const f4*>(&wv2[lane * 8 + 4]);
    for (int rr = 0; rr < 16; ++rr) {
      int i = r0 + wid * 16 + rr;
      f4 xa = *reinterpret_cast<const f4*>(&X[(size_t)i * KDIM + lane * 8]);
      f4 xb = *reinterpret_cast<const f4*>(&X[(size_t)i * KDIM + lane * 8 + 4]);
      float p1 = dot4(xa, w1a) + dot4(xb, w1b);
      float p2 = dot4(xa, w2a) + dot4(xb, w2b);
      for (int off = 32; off > 0; off >>= 1) {
        p1 += __shfl_down(p1, off);
        p2 += __shfl_down(p2, off);
      }
      if (lane == 0) { s[i] = p1; t[i] = p2; }
    }
  }
}

// ---------- K2: tmax, E/c (16 rows), rank 16 keys + ki-count 16 rows ----------
// 512 blocks. Streams all of t once per block; counts both the sorted rank of
// its 16 t-keys AND ki = #{j: t_j <= -s_i} for its 16 rows. Scatters sorted-
// order exp arrays Es1/Es2 alongside tsort/perm.
__global__ __launch_bounds__(256) void k_mid(const float* __restrict__ s,
                                             const float* __restrict__ t,
                                             float* __restrict__ E1,
                                             float* __restrict__ E2,
                                             float* __restrict__ c1,
                                             float* __restrict__ c2,
                                             float* __restrict__ tsort,
                                             int* __restrict__ perm,
                                             float* __restrict__ Es1,
                                             float* __restrict__ Es2,
                                             int* __restrict__ kidx) {
  __shared__ float lred[4];
  const int b = blockIdx.x, tid = threadIdx.x;
  const int wid = tid >> 6, lane = tid & 63;
  float m = -1e30f;
#pragma unroll
  for (int q = 0; q < 8; ++q) {
    int idx = (q * 256 + tid) * 4;
    f4 v = *reinterpret_cast<const f4*>(&t[idx]);
    m = fmaxf(m, fmaxf(fmaxf(v.x, v.y), fmaxf(v.z, v.w)));
  }
  for (int off = 32; off > 0; off >>= 1) m = fmaxf(m, __shfl_down(m, off));
  if (lane == 0) lred[wid] = m;
  __syncthreads();
  float tmax = fmaxf(fmaxf(lred[0], lred[1]), fmaxf(lred[2], lred[3]));

  if (tid < 16) {
    int i = b * 16 + tid;
    float ti = t[i];
    E1[i] = expf(ti);
    E2[i] = expf(0.2f * ti);
    float si = s[i];
    float e = si + tmax;
    float mm = e > 0.f ? e : 0.2f * e;
    c1[i] = expf(si - mm);
    c2[i] = expf(0.2f * si - mm);
  }

  // 4 rank keys + 4 s-keys per wave
  float tkv[4], skv[4]; int jj[4], cnt[4], cntk[4];
#pragma unroll
  for (int q = 0; q < 4; ++q) {
    jj[q] = b * 16 + wid * 4 + q;
    tkv[q] = t[jj[q]];
    skv[q] = -s[jj[q]];
    cnt[q] = 0;
    cntk[q] = 0;
  }
  for (int m2 = 0; m2 < 32; ++m2) {
    int i4 = m2 * 64 + lane;
    f4 v = *reinterpret_cast<const f4*>(&t[i4 * 4]);
    int base = i4 * 4;
#pragma unroll
    for (int q = 0; q < 4; ++q) {
      cnt[q] += (v.x < tkv[q]) || (v.x == tkv[q] && base + 0 < jj[q]);
      cnt[q] += (v.y < tkv[q]) || (v.y == tkv[q] && base + 1 < jj[q]);
      cnt[q] += (v.z < tkv[q]) || (v.z == tkv[q] && base + 2 < jj[q]);
      cnt[q] += (v.w < tkv[q]) || (v.w == tkv[q] && base + 3 < jj[q]);
      cntk[q] += (v.x <= skv[q]) + (v.y <= skv[q]) + (v.z <= skv[q]) + (v.w <= skv[q]);
    }
  }
#pragma unroll
  for (int q = 0; q < 4; ++q) {
    int c = cnt[q], ck = cntk[q];
    for (int off = 32; off > 0; off >>= 1) {
      c += __shfl_down(c, off);
      ck += __shfl_down(ck, off);
    }
    if (lane == 0) {
      tsort[c] = tkv[q];
      perm[c] = jj[q];
      Es1[c] = expf(tkv[q]);        // bitwise == E1[jj[q]]
      Es2[c] = expf(0.2f * tkv[q]);
      kidx[jj[q]] = ck;
    }
  }
}

// ---------- K3: per-chunk totals over sorted order + gather Hs ----------
__global__ __launch_bounds__(256) void k_chunk(const float* __restrict__ H,
                                               const float* __restrict__ Es1,
                                               const float* __restrict__ Es2,
                                               const int* __restrict__ perm,
                                               float* __restrict__ Hs,
                                               float* __restrict__ Ctot1,
                                               float* __restrict__ Ctot2,
                                               float* __restrict__ cs1,
                                               float* __restrict__ cs2) {
  __shared__ int pms[CS];
  int c = blockIdx.x;
  int d = threadIdx.x;
  if (d < CS) pms[d] = perm[c * CS + d];
  __syncthreads();
  float s1 = 0.f, s2 = 0.f, a1 = 0.f, a2 = 0.f;
#pragma unroll 4
  for (int kk = 0; kk < CS; ++kk) {
    int mI = c * CS + kk;
    float e1 = Es1[mI], e2 = Es2[mI];
    float h = H[(size_t)pms[kk] * DD + d];
    Hs[(size_t)mI * DD + d] = h;
    s1 += e1 * h; s2 += e2 * h;
    a1 += e1;     a2 += e2;
  }
  Ctot1[c * DD + d] = s1;
  Ctot2[c * DD + d] = s2;
  if (d == 0) { cs1[c] = a1; cs2[c] = a2; }
}

// ---------- K4: Cpre (triangular, pipelined) + scalar csp + f1/f2 ----------
__global__ __launch_bounds__(256) void k_scan(const float* __restrict__ Ctot1,
                                              const float* __restrict__ Ctot2,
                                              const float* __restrict__ cs1,
                                              const float* __restrict__ cs2,
                                              const float* __restrict__ Es1,
                                              const float* __restrict__ Es2,
                                              const int* __restrict__ kidx,
                                              const float* __restrict__ c1,
                                              const float* __restrict__ c2,
                                              float* __restrict__ Cpre1,
                                              float* __restrict__ Cpre2,
                                              float* __restrict__ f1,
                                              float* __restrict__ f2) {
  __shared__ float sc1[NC], sc2[NC];
  const int c = blockIdx.x;
  const int d = threadIdx.x;
  // vector triangular: Cpre[c][d] = sum_{cc<c} Ctot[cc][d]
  float r1a = 0.f, r1b = 0.f, r2a = 0.f, r2b = 0.f;
  int cc = 0;
  for (; cc + 4 <= c; cc += 4) {
    r1a += Ctot1[(cc + 0) * DD + d];
    r1b += Ctot1[(cc + 1) * DD + d];
    r1a += Ctot1[(cc + 2) * DD + d];
    r1b += Ctot1[(cc + 3) * DD + d];
    r2a += Ctot2[(cc + 0) * DD + d];
    r2b += Ctot2[(cc + 1) * DD + d];
    r2a += Ctot2[(cc + 2) * DD + d];
    r2b += Ctot2[(cc + 3) * DD + d];
  }
  for (; cc < c; ++cc) {
    r1a += Ctot1[cc * DD + d];
    r2a += Ctot2[cc * DD + d];
  }
  float r1 = r1a + r1b, r2 = r2a + r2b;
  Cpre1[(size_t)c * DD + d] = r1;
  Cpre2[(size_t)c * DD + d] = r2;
  if (c == NC - 1) {
    Cpre1[(size_t)NC * DD + d] = r1 + Ctot1[c * DD + d];
    Cpre2[(size_t)NC * DD + d] = r2 + Ctot2[c * DD + d];
  }
  // scalar inclusive scan of cs in LDS (Hillis-Steele)
  sc1[d] = cs1[d];
  sc2[d] = cs2[d];
  __syncthreads();
  for (int off = 1; off < NC; off <<= 1) {
    float y1 = (d >= off) ? sc1[d - off] : 0.f;
    float y2 = (d >= off) ? sc2[d - off] : 0.f;
    __syncthreads();
    sc1[d] += y1; sc2[d] += y2;
    __syncthreads();
  }
  // f1/f2 for rows c*32..c*32+31
  if (d < 32) {
    int i = c * 32 + d;
    int ki = kidx[i];
    int ci = ki >> 5;
    float sp1 = ci ? sc1[ci - 1] : 0.f;
    float sp2 = ci ? sc2[ci - 1] : 0.f;
    for (int m = ci * CS; m < ki; ++m) { sp1 += Es1[m]; sp2 += Es2[m]; }
    float T1s = sc1[NC - 1];
    float a1 = c1[i], a2 = c2[i];
    float Z = a1 * (T1s - sp1) + a2 * sp2;
    float rZ = 1.0f / Z;
    f1[i] = rZ * a1;
    f2[i] = rZ * a2;
  }
}

// ---------- K5: finalize out rows (4 rows/block, contiguous Es/Hs) ----------
__global__ __launch_bounds__(256) void k_fin2(const int* __restrict__ kidx,
                                              const float* __restrict__ Es1,
                                              const float* __restrict__ Es2,
                                              const float* __restrict__ Hs,
                                              const float* __restrict__ Cpre1,
                                              const float* __restrict__ Cpre2,
                                              const float* __restrict__ f1,
                                              const float* __restrict__ f2,
                                              float* __restrict__ out) {
  const int b = blockIdx.x;
  const int d = threadIdx.x;
  float T1 = Cpre1[(size_t)NC * DD + d];
#pragma unroll
  for (int r = 0; r < 4; ++r) {
    int i = b * 4 + r;
    int ki = kidx[i];
    int ci = ki >> 5;
    float P1 = Cpre1[(size_t)ci * DD + d];
    float P2 = Cpre2[(size_t)ci * DD + d];
    for (int m = ci * CS; m < ki; ++m) {
      float h = Hs[(size_t)m * DD + d];
      P1 += Es1[m] * h;
      P2 += Es2[m] * h;
    }
    out[(size_t)i * DD + d] = f1[i] * (T1 - P1) + f2[i] * P2;
  }
}

// ---------- K6: stream A = (s_i + t_j > 0) ? f1_i*E1_j : f2_i*E2_j ----------
__global__ __launch_bounds__(256) void k_astream(const float* __restrict__ s,
                                                 const float* __restrict__ t,
                                                 const float* __restrict__ E1,
                                                 const float* __restrict__ E2,
                                                 const float* __restrict__ f1,
                                                 const float* __restrict__ f2,
                                                 float* __restrict__ A) {
  int j0 = blockIdx.x * 1024 + threadIdx.x * 4;
  int i0 = blockIdx.y * 32;
  f4 t4  = *reinterpret_cast<const f4*>(&t[j0]);
  f4 e14 = *reinterpret_cast<const f4*>(&E1[j0]);
  f4 e24 = *reinterpret_cast<const f4*>(&E2[j0]);
#pragma unroll 4
  for (int rr = 0; rr < 32; ++rr) {
    int i = i0 + rr;
    float ss = s[i], ff1 = f1[i], ff2 = f2[i];
    f4v o;
    float e;
    e = ss + t4.x; o.x = (e > 0.f) ? ff1 * e14.x : ff2 * e24.x;
    e = ss + t4.y; o.y = (e > 0.f) ? ff1 * e14.y : ff2 * e24.y;
    e = ss + t4.z; o.z = (e > 0.f) ? ff1 * e14.z : ff2 * e24.z;
    e = ss + t4.w; o.w = (e > 0.f) ? ff1 * e14.w : ff2 * e24.w;
    __builtin_nontemporal_store(o, reinterpret_cast<f4v*>(&A[(size_t)i * NN + j0]));
  }
}

extern "C" void kernel_launch(void* const* d_in, const int* in_sizes, int n_in,
                              void* d_out, int out_size, void* d_ws, size_t ws_size,
                              hipStream_t stream) {
  const float* X  = (const float*)d_in[0];
  const float* W  = (const float*)d_in[1];
  const float* av = (const float*)d_in[2];
  float* outp = (float*)d_out;                  // [NN*DD]
  float* A = outp + (size_t)NN * DD;            // [NN*NN]

  // small vectors in ws (256 KB, proven size)
  float* wsp = (float*)d_ws;
  float* s  = wsp + 0 * NN;
  float* t  = wsp + 1 * NN;
  float* E1 = wsp + 2 * NN;
  float* E2 = wsp + 3 * NN;
  float* c1 = wsp + 4 * NN;
  float* c2 = wsp + 5 * NN;
  float* f1 = wsp + 6 * NN;
  float* f2 = wsp + 7 * NN;

  // scratch in the A-region (all consumed by k_fin2, before k_astream writes A)
  float* Ctot1 = A;                       // 65536
  float* Ctot2 = A + 65536;               // 65536
  float* Cpre1 = A + 131072;              // 65792 (257*256)
  float* Cpre2 = A + 196864;              // 65792
  float* cs1   = A + 262656;              // 256
  float* cs2   = A + 262912;              // 256
  float* tsort = A + 263168;              // 8192
  int*   perm  = (int*)(A + 271360);      // 8192
  int*   kidx  = (int*)(A + 279552);      // 8192
  float* Es1   = A + 287744;              // 8192
  float* Es2   = A + 295936;              // 8192
  float* H     = A + 16777216;            // 2M floats
  float* Hs    = A + 20971520;            // 2M floats (sorted-order H)

  k_gemm<<<dim3(NN / 64, DD / 64), 256, 0, stream>>>(X, W, av, H, s, t);
  k_mid<<<NN / 16, 256, 0, stream>>>(s, t, E1, E2, c1, c2, tsort, perm,
                                     Es1, Es2, kidx);
  k_chunk<<<NC, 256, 0, stream>>>(H, Es1, Es2, perm, Hs, Ctot1, Ctot2, cs1, cs2);
  k_scan<<<NC, 256, 0, stream>>>(Ctot1, Ctot2, cs1, cs2, Es1, Es2, kidx, c1, c2,
                                 Cpre1, Cpre2, f1, f2);
  k_fin2<<<NN / 4, 256, 0, stream>>>(kidx, Es1, Es2, Hs, Cpre1, Cpre2, f1, f2, outp);
  k_astream<<<dim3(NN / 1024, NN / 32), 256, 0, stream>>>(s, t, E1, E2, f1, f2, A);
}

// Round 11
// 183.924 us; speedup vs baseline: 3.6056x; 1.0744x over previous
//
#include <hip/hip_runtime.h>
#include <math.h>

#define NN 8192
#define KDIM 512
#define DD 256
#define CS 32      // prefix chunk size
#define NC 256     // number of chunks

typedef float4 f4;
typedef __attribute__((ext_vector_type(4))) float f4v;  // native vec for nontemporal

__device__ __forceinline__ float dot4(const f4& x, const f4& y) {
  return x.x * y.x + x.y * y.y + x.z * y.z + x.w * y.w;
}

// ---------- K1: H = X @ W (f32 vector GEMM, 64x64 tile) + s,t tail ----------
__global__ __launch_bounds__(256) void k_gemm(const float* __restrict__ X,
                                              const float* __restrict__ W,
                                              const float* __restrict__ av,
                                              float* __restrict__ H,
                                              float* __restrict__ s,
                                              float* __restrict__ t) {
  __shared__ float Xs[32][64];  // [k][r] (transposed); reused as wv1/wv2 after
  __shared__ float Ws[32][64];  // [k][c]
  const int tid = threadIdx.x;
  const int tx = tid & 15;
  const int ty = tid >> 4;
  const int r0 = blockIdx.x * 64;
  const int c0 = blockIdx.y * 64;
  float acc[4][4] = {};
  for (int k0 = 0; k0 < KDIM; k0 += 32) {
#pragma unroll
    for (int q = 0; q < 2; ++q) {
      int fi = tid + q * 256;
      int r = fi >> 3;
      int kq = fi & 7;
      f4 v = *reinterpret_cast<const f4*>(&X[(size_t)(r0 + r) * KDIM + k0 + kq * 4]);
      Xs[kq * 4 + 0][r] = v.x; Xs[kq * 4 + 1][r] = v.y;
      Xs[kq * 4 + 2][r] = v.z; Xs[kq * 4 + 3][r] = v.w;
    }
#pragma unroll
    for (int q = 0; q < 2; ++q) {
      int fi = tid + q * 256;
      int k = fi >> 4;
      int cq = fi & 15;
      *reinterpret_cast<f4*>(&Ws[k][cq * 4]) =
          *reinterpret_cast<const f4*>(&W[(size_t)(k0 + k) * DD + c0 + cq * 4]);
    }
    __syncthreads();
#pragma unroll
    for (int k = 0; k < 32; ++k) {
      f4 xv = *reinterpret_cast<const f4*>(&Xs[k][ty * 4]);
      f4 wv = *reinterpret_cast<const f4*>(&Ws[k][tx * 4]);
      float xs[4] = {xv.x, xv.y, xv.z, xv.w};
      float ws[4] = {wv.x, wv.y, wv.z, wv.w};
#pragma unroll
      for (int i = 0; i < 4; ++i)
#pragma unroll
        for (int j = 0; j < 4; ++j) acc[i][j] += xs[i] * ws[j];
    }
    __syncthreads();
  }
#pragma unroll
  for (int i = 0; i < 4; ++i) {
    f4 v = {acc[i][0], acc[i][1], acc[i][2], acc[i][3]};
    *reinterpret_cast<f4*>(&H[(size_t)(r0 + ty * 4 + i) * DD + c0 + tx * 4]) = v;
  }

  if (c0 == 0) {
    // s,t for rows r0..r0+63 via s = X@(W@a1), t = X@(W@a2)
    int wid = tid >> 6, lane = tid & 63;
    float* wv1 = &Xs[0][0];        // [512]
    float* wv2 = &Xs[0][0] + 512;  // [512]
    for (int k = tid; k < KDIM; k += 256) {
      float a1acc = 0.f, a2acc = 0.f;
#pragma unroll 8
      for (int d4 = 0; d4 < DD / 4; ++d4) {
        f4 wrow = *reinterpret_cast<const f4*>(&W[(size_t)k * DD + d4 * 4]);
        f4 a1v = *reinterpret_cast<const f4*>(&av[d4 * 4]);
        f4 a2v = *reinterpret_cast<const f4*>(&av[DD + d4 * 4]);
        a1acc += dot4(wrow, a1v);
        a2acc += dot4(wrow, a2v);
      }
      wv1[k] = a1acc;
      wv2[k] = a2acc;
    }
    __syncthreads();
    f4 w1a = *reinterpret_cast<const f4*>(&wv1[lane * 8]);
    f4 w1b = *reinterpret_cast<const f4*>(&wv1[lane * 8 + 4]);
    f4 w2a = *reinterpret_cast<const f4*>(&wv2[lane * 8]);
    f4 w2b = *reinterpret_cast<const f4*>(&wv2[lane * 8 + 4]);
    for (int rr = 0; rr < 16; ++rr) {
      int i = r0 + wid * 16 + rr;
      f4 xa = *reinterpret_cast<const f4*>(&X[(size_t)i * KDIM + lane * 8]);
      f4 xb = *reinterpret_cast<const f4*>(&X[(size_t)i * KDIM + lane * 8 + 4]);
      float p1 = dot4(xa, w1a) + dot4(xb, w1b);
      float p2 = dot4(xa, w2a) + dot4(xb, w2b);
      for (int off = 32; off > 0; off >>= 1) {
        p1 += __shfl_down(p1, off);
        p2 += __shfl_down(p2, off);
      }
      if (lane == 0) { s[i] = p1; t[i] = p2; }
    }
  }
}

// ---------- K2: tmax, E/c (16 rows), rank 16 keys + ki-count 16 rows ----------
__global__ __launch_bounds__(256) void k_mid(const float* __restrict__ s,
                                             const float* __restrict__ t,
                                             float* __restrict__ E1,
                                             float* __restrict__ E2,
                                             float* __restrict__ c1,
                                             float* __restrict__ c2,
                                             int* __restrict__ perm,
                                             float* __restrict__ Es1,
                                             float* __restrict__ Es2,
                                             int* __restrict__ kidx) {
  __shared__ float lred[4];
  const int b = blockIdx.x, tid = threadIdx.x;
  const int wid = tid >> 6, lane = tid & 63;
  float m = -1e30f;
#pragma unroll
  for (int q = 0; q < 8; ++q) {
    int idx = (q * 256 + tid) * 4;
    f4 v = *reinterpret_cast<const f4*>(&t[idx]);
    m = fmaxf(m, fmaxf(fmaxf(v.x, v.y), fmaxf(v.z, v.w)));
  }
  for (int off = 32; off > 0; off >>= 1) m = fmaxf(m, __shfl_down(m, off));
  if (lane == 0) lred[wid] = m;
  __syncthreads();
  float tmax = fmaxf(fmaxf(lred[0], lred[1]), fmaxf(lred[2], lred[3]));

  if (tid < 16) {
    int i = b * 16 + tid;
    float ti = t[i];
    E1[i] = expf(ti);
    E2[i] = expf(0.2f * ti);
    float si = s[i];
    float e = si + tmax;
    float mm = e > 0.f ? e : 0.2f * e;
    c1[i] = expf(si - mm);
    c2[i] = expf(0.2f * si - mm);
  }

  // 4 rank keys + 4 s-keys per wave
  float tkv[4], skv[4]; int jj[4], cnt[4], cntk[4];
#pragma unroll
  for (int q = 0; q < 4; ++q) {
    jj[q] = b * 16 + wid * 4 + q;
    tkv[q] = t[jj[q]];
    skv[q] = -s[jj[q]];
    cnt[q] = 0;
    cntk[q] = 0;
  }
  for (int m2 = 0; m2 < 32; ++m2) {
    int i4 = m2 * 64 + lane;
    f4 v = *reinterpret_cast<const f4*>(&t[i4 * 4]);
    int base = i4 * 4;
#pragma unroll
    for (int q = 0; q < 4; ++q) {
      cnt[q] += (v.x < tkv[q]) || (v.x == tkv[q] && base + 0 < jj[q]);
      cnt[q] += (v.y < tkv[q]) || (v.y == tkv[q] && base + 1 < jj[q]);
      cnt[q] += (v.z < tkv[q]) || (v.z == tkv[q] && base + 2 < jj[q]);
      cnt[q] += (v.w < tkv[q]) || (v.w == tkv[q] && base + 3 < jj[q]);
      cntk[q] += (v.x <= skv[q]) + (v.y <= skv[q]) + (v.z <= skv[q]) + (v.w <= skv[q]);
    }
  }
#pragma unroll
  for (int q = 0; q < 4; ++q) {
    int c = cnt[q], ck = cntk[q];
    for (int off = 32; off > 0; off >>= 1) {
      c += __shfl_down(c, off);
      ck += __shfl_down(ck, off);
    }
    if (lane == 0) {
      perm[c] = jj[q];
      Es1[c] = expf(tkv[q]);        // bitwise == E1[jj[q]]
      Es2[c] = expf(0.2f * tkv[q]);
      kidx[jj[q]] = ck;
    }
  }
}

// ---------- K3: per-chunk totals of Es*H(perm) over sorted order ----------
__global__ __launch_bounds__(256) void k_chunk(const float* __restrict__ H,
                                               const float* __restrict__ Es1,
                                               const float* __restrict__ Es2,
                                               const int* __restrict__ perm,
                                               float* __restrict__ Ctot1,
                                               float* __restrict__ Ctot2,
                                               float* __restrict__ cs1,
                                               float* __restrict__ cs2) {
  __shared__ int pms[CS];
  int c = blockIdx.x;
  int d = threadIdx.x;
  if (d < CS) pms[d] = perm[c * CS + d];
  __syncthreads();
  float s1 = 0.f, s2 = 0.f, a1 = 0.f, a2 = 0.f;
#pragma unroll 4
  for (int kk = 0; kk < CS; ++kk) {
    int mI = c * CS + kk;
    float e1 = Es1[mI], e2 = Es2[mI];
    float h = H[(size_t)pms[kk] * DD + d];
    s1 += e1 * h; s2 += e2 * h;
    a1 += e1;     a2 += e2;
  }
  Ctot1[c * DD + d] = s1;
  Ctot2[c * DD + d] = s2;
  if (d == 0) { cs1[c] = a1; cs2[c] = a2; }
}

// ---------- K4: Cpre (triangular, pipelined) + scalar csp + f1/f2 ----------
__global__ __launch_bounds__(256) void k_scan(const float* __restrict__ Ctot1,
                                              const float* __restrict__ Ctot2,
                                              const float* __restrict__ cs1,
                                              const float* __restrict__ cs2,
                                              const float* __restrict__ Es1,
                                              const float* __restrict__ Es2,
                                              const int* __restrict__ kidx,
                                              const float* __restrict__ c1,
                                              const float* __restrict__ c2,
                                              float* __restrict__ Cpre1,
                                              float* __restrict__ Cpre2,
                                              float* __restrict__ f1,
                                              float* __restrict__ f2) {
  __shared__ float sc1[NC], sc2[NC];
  const int c = blockIdx.x;
  const int d = threadIdx.x;
  float r1a = 0.f, r1b = 0.f, r2a = 0.f, r2b = 0.f;
  int cc = 0;
  for (; cc + 4 <= c; cc += 4) {
    r1a += Ctot1[(cc + 0) * DD + d];
    r1b += Ctot1[(cc + 1) * DD + d];
    r1a += Ctot1[(cc + 2) * DD + d];
    r1b += Ctot1[(cc + 3) * DD + d];
    r2a += Ctot2[(cc + 0) * DD + d];
    r2b += Ctot2[(cc + 1) * DD + d];
    r2a += Ctot2[(cc + 2) * DD + d];
    r2b += Ctot2[(cc + 3) * DD + d];
  }
  for (; cc < c; ++cc) {
    r1a += Ctot1[cc * DD + d];
    r2a += Ctot2[cc * DD + d];
  }
  float r1 = r1a + r1b, r2 = r2a + r2b;
  Cpre1[(size_t)c * DD + d] = r1;
  Cpre2[(size_t)c * DD + d] = r2;
  if (c == NC - 1) {
    Cpre1[(size_t)NC * DD + d] = r1 + Ctot1[c * DD + d];
    Cpre2[(size_t)NC * DD + d] = r2 + Ctot2[c * DD + d];
  }
  sc1[d] = cs1[d];
  sc2[d] = cs2[d];
  __syncthreads();
  for (int off = 1; off < NC; off <<= 1) {
    float y1 = (d >= off) ? sc1[d - off] : 0.f;
    float y2 = (d >= off) ? sc2[d - off] : 0.f;
    __syncthreads();
    sc1[d] += y1; sc2[d] += y2;
    __syncthreads();
  }
  if (d < 32) {
    int i = c * 32 + d;
    int ki = kidx[i];
    int ci = ki >> 5;
    float sp1 = ci ? sc1[ci - 1] : 0.f;
    float sp2 = ci ? sc2[ci - 1] : 0.f;
    for (int m = ci * CS; m < ki; ++m) { sp1 += Es1[m]; sp2 += Es2[m]; }
    float T1s = sc1[NC - 1];
    float a1 = c1[i], a2 = c2[i];
    float Z = a1 * (T1s - sp1) + a2 * sp2;
    float rZ = 1.0f / Z;
    f1[i] = rZ * a1;
    f2[i] = rZ * a2;
  }
}

// ---- shared fin core: 4 rows starting at i0 ----
__device__ __forceinline__ void fin_rows(int i0, int d,
                                         const int* __restrict__ kidx,
                                         const float* __restrict__ Es1,
                                         const float* __restrict__ Es2,
                                         const int* __restrict__ perm,
                                         const float* __restrict__ H,
                                         const float* __restrict__ Cpre1,
                                         const float* __restrict__ Cpre2,
                                         const float* __restrict__ f1,
                                         const float* __restrict__ f2,
                                         float* __restrict__ out) {
  float T1 = Cpre1[(size_t)NC * DD + d];
#pragma unroll
  for (int r = 0; r < 4; ++r) {
    int i = i0 + r;
    int ki = kidx[i];
    int ci = ki >> 5;
    float P1 = Cpre1[(size_t)ci * DD + d];
    float P2 = Cpre2[(size_t)ci * DD + d];
    for (int m = ci * CS; m < ki; ++m) {
      float h = H[(size_t)perm[m] * DD + d];
      P1 += Es1[m] * h;
      P2 += Es2[m] * h;
    }
    out[(size_t)i * DD + d] = f1[i] * (T1 - P1) + f2[i] * P2;
  }
}

// ---- shared astream core: 32 rows x 1024 cols ----
__device__ __forceinline__ void astream_tile(int i0, int j0,
                                             const float* __restrict__ s,
                                             const float* __restrict__ t,
                                             const float* __restrict__ E1,
                                             const float* __restrict__ E2,
                                             const float* __restrict__ f1,
                                             const float* __restrict__ f2,
                                             float* __restrict__ A) {
  f4 t4  = *reinterpret_cast<const f4*>(&t[j0]);
  f4 e14 = *reinterpret_cast<const f4*>(&E1[j0]);
  f4 e24 = *reinterpret_cast<const f4*>(&E2[j0]);
#pragma unroll 4
  for (int rr = 0; rr < 32; ++rr) {
    int i = i0 + rr;
    float ss = s[i], ff1 = f1[i], ff2 = f2[i];
    f4v o;
    float e;
    e = ss + t4.x; o.x = (e > 0.f) ? ff1 * e14.x : ff2 * e24.x;
    e = ss + t4.y; o.y = (e > 0.f) ? ff1 * e14.y : ff2 * e24.y;
    e = ss + t4.z; o.z = (e > 0.f) ? ff1 * e14.z : ff2 * e24.z;
    e = ss + t4.w; o.w = (e > 0.f) ? ff1 * e14.w : ff2 * e24.w;
    __builtin_nontemporal_store(o, reinterpret_cast<f4v*>(&A[(size_t)i * NN + j0]));
  }
}

// ---------- K5 (fast path): merged finalize + A-stream, 2048 blocks ----------
__global__ __launch_bounds__(256) void k_finstream(const int* __restrict__ kidx,
                                                   const float* __restrict__ Es1,
                                                   const float* __restrict__ Es2,
                                                   const int* __restrict__ perm,
                                                   const float* __restrict__ H,
                                                   const float* __restrict__ Cpre1,
                                                   const float* __restrict__ Cpre2,
                                                   const float* __restrict__ f1,
                                                   const float* __restrict__ f2,
                                                   float* __restrict__ out,
                                                   const float* __restrict__ s,
                                                   const float* __restrict__ t,
                                                   const float* __restrict__ E1,
                                                   const float* __restrict__ E2,
                                                   float* __restrict__ A) {
  const int bb = blockIdx.x;
  const int d = threadIdx.x;
  fin_rows(bb * 4, d, kidx, Es1, Es2, perm, H, Cpre1, Cpre2, f1, f2, out);
  astream_tile((bb >> 3) * 32, (bb & 7) * 1024 + d * 4, s, t, E1, E2, f1, f2, A);
}

// ---------- fallback path kernels ----------
__global__ __launch_bounds__(256) void k_fin2(const int* __restrict__ kidx,
                                              const float* __restrict__ Es1,
                                              const float* __restrict__ Es2,
                                              const int* __restrict__ perm,
                                              const float* __restrict__ H,
                                              const float* __restrict__ Cpre1,
                                              const float* __restrict__ Cpre2,
                                              const float* __restrict__ f1,
                                              const float* __restrict__ f2,
                                              float* __restrict__ out) {
  fin_rows(blockIdx.x * 4, threadIdx.x, kidx, Es1, Es2, perm, H, Cpre1, Cpre2,
           f1, f2, out);
}

__global__ __launch_bounds__(256) void k_astream(const float* __restrict__ s,
                                                 const float* __restrict__ t,
                                                 const float* __restrict__ E1,
                                                 const float* __restrict__ E2,
                                                 const float* __restrict__ f1,
                                                 const float* __restrict__ f2,
                                                 float* __restrict__ A) {
  astream_tile(blockIdx.y * 32, blockIdx.x * 1024 + threadIdx.x * 4,
               s, t, E1, E2, f1, f2, A);
}

extern "C" void kernel_launch(void* const* d_in, const int* in_sizes, int n_in,
                              void* d_out, int out_size, void* d_ws, size_t ws_size,
                              hipStream_t stream) {
  const float* X  = (const float*)d_in[0];
  const float* W  = (const float*)d_in[1];
  const float* av = (const float*)d_in[2];
  float* outp = (float*)d_out;                  // [NN*DD]
  float* A = outp + (size_t)NN * DD;            // [NN*NN]
  float* wsp = (float*)d_ws;

  // common small vectors in ws (first 256 KB)
  float* s  = wsp + 0 * NN;
  float* t  = wsp + 1 * NN;
  float* E1 = wsp + 2 * NN;
  float* E2 = wsp + 3 * NN;
  float* c1 = wsp + 4 * NN;
  float* c2 = wsp + 5 * NN;
  float* f1 = wsp + 6 * NN;
  float* f2 = wsp + 7 * NN;

  // fast path needs scratch + H fully inside ws (so nothing lives in A and
  // the merged fin+astream kernel can run without ordering hazards)
  const size_t FAST_WS_FLOATS = 393216 + (size_t)NN * DD;  // ~9.96 MB
  if (ws_size >= FAST_WS_FLOATS * sizeof(float)) {
    float* Ctot1 = wsp + 65536;
    float* Ctot2 = wsp + 131072;
    float* Cpre1 = wsp + 196608;            // 257*256
    float* Cpre2 = wsp + 262400;
    float* cs1   = wsp + 328192;
    float* cs2   = wsp + 328448;
    float* Es1   = wsp + 328704;
    float* Es2   = wsp + 336896;
    int*   kidx  = (int*)(wsp + 345088);
    int*   perm  = (int*)(wsp + 353280);
    float* H     = wsp + 393216;            // 2M floats

    k_gemm<<<dim3(NN / 64, DD / 64), 256, 0, stream>>>(X, W, av, H, s, t);
    k_mid<<<NN / 16, 256, 0, stream>>>(s, t, E1, E2, c1, c2, perm, Es1, Es2, kidx);
    k_chunk<<<NC, 256, 0, stream>>>(H, Es1, Es2, perm, Ctot1, Ctot2, cs1, cs2);
    k_scan<<<NC, 256, 0, stream>>>(Ctot1, Ctot2, cs1, cs2, Es1, Es2, kidx, c1, c2,
                                   Cpre1, Cpre2, f1, f2);
    k_finstream<<<NN / 4, 256, 0, stream>>>(kidx, Es1, Es2, perm, H, Cpre1, Cpre2,
                                            f1, f2, outp, s, t, E1, E2, A);
  } else {
    // fallback: scratch in A-region (R10 structure)
    float* Ctot1 = A;
    float* Ctot2 = A + 65536;
    float* Cpre1 = A + 131072;
    float* Cpre2 = A + 196864;
    float* cs1   = A + 262656;
    float* cs2   = A + 262912;
    int*   perm  = (int*)(A + 271360);
    int*   kidx  = (int*)(A + 279552);
    float* Es1   = A + 287744;
    float* Es2   = A + 295936;
    float* H     = A + 16777216;

    k_gemm<<<dim3(NN / 64, DD / 64), 256, 0, stream>>>(X, W, av, H, s, t);
    k_mid<<<NN / 16, 256, 0, stream>>>(s, t, E1, E2, c1, c2, perm, Es1, Es2, kidx);
    k_chunk<<<NC, 256, 0, stream>>>(H, Es1, Es2, perm, Ctot1, Ctot2, cs1, cs2);
    k_scan<<<NC, 256, 0, stream>>>(Ctot1, Ctot2, cs1, cs2, Es1, Es2, kidx, c1, c2,
                                   Cpre1, Cpre2, f1, f2);
    k_fin2<<<NN / 4, 256, 0, stream>>>(kidx, Es1, Es2, perm, H, Cpre1, Cpre2,
                                       f1, f2, outp);
    k_astream<<<dim3(NN / 1024, NN / 32), 256, 0, stream>>>(s, t, E1, E2, f1, f2, A);
  }
}